// Round 6
// baseline (308.308 us; speedup 1.0000x reference)
//
#include <hip/hip_runtime.h>

// Cost volume: out[b,d,h,w] = (w>=d) ? (1/32) * sum_c L[b,c,h,w]*R[b,c,h,w-d] : 0
// B=4, C=32, H=256, W=512, D=64, fp32 (no fp32-input MFMA on CDNA4).
//
// v6 (autonomy + occupancy): v5 proved wave-autonomous execution sustains
// ~2.4x the per-wave throughput of any barrier-phased version (6 waves/CU ->
// 104us vs 16 waves -> 94us), but collapsed residency. v6 keeps ZERO
// barriers and restores 16 waves/CU:
//   - 512-thr block = 8 autonomous waves, wave = (d-quarter, w-half).
//   - DT=16 x WT=4 per thread (acc 64 regs; VGPR ~118 < 128 cap of
//     __launch_bounds__(512,4) -> 2 blocks/CU = 16 waves/CU; grid 1024 =
//     exactly 2 residency rounds).
//   - Per-wave PRIVATE 3-slot ring, 384-float half-row slots (block LDS
//     36.9KB). Slot coord s = w - wh + 128; wh=0 waves keep s<128 zeroed
//     (w<d masking), DMA never touches it.
//   - L: direct global->register float4 ring (prefetch 2 ahead), off LDS.
//   - Counted per-wave vmcnt (never 0 mid-loop), full unroll -> all ring
//     indices and waitcnt literals compile-time. lgkmcnt(0) before each
//     stage orders prior ds_reads vs the DMA overwrite of the freed slot.
// Cost accepted: R staged per (dq,wh) wave -> 5x R reads (~670MB, L2/L3-
// served). Per-CU: LDS ~34us, VALU ~14us, HBM ~30us, overlapped by 16
// self-paced waves.

constexpr int Bn = 4, Cn = 32, Hn = 256, Wn = 512, Dn = 64;
constexpr int HW = Hn * Wn;          // 131072
constexpr int SLOTF = 384;           // floats per ring slot
constexpr int NSLOT = 3;             // ring depth (2 chunks ahead)
constexpr int WAVE_LDS = NSLOT * SLOTF;  // 1152 floats = 4608 B per wave

// NR = R-DMA instrs per chunk: 1 for wh=0 (data w[0,256)), 2 for wh=256
// (data w[128,512), two overlapping 1KB transfers).
template<int NR>
__device__ __forceinline__ void run_wave(
    const float* __restrict__ Lrow, const float* __restrict__ Rrow,
    float* __restrict__ out, float* ring,
    const int lane, const int d0, const int wh, const int b, const int h)
{
    const int l4 = lane << 2;
    const int w0 = wh + l4;

    // zero pads (wh=0 only): s in [0,128) of each of the 3 slots = 96 float4
    if (NR == 1) {
        #pragma unroll
        for (int k = 0; k < 2; ++k) {
            const int idx = lane + (k << 6);
            if (idx < NSLOT * 32) {
                const int slot = idx >> 5;
                const int o = (idx & 31) << 2;
                *reinterpret_cast<float4*>(&ring[slot * SLOTF + o]) =
                    make_float4(0.f, 0.f, 0.f, 0.f);
            }
        }
    }

    // stage chunk c -> slot. LDS dest = wave-uniform base + lane*16 (legal).
    auto stageR = [&](int slot, int c) {
        float* base = &ring[slot * SLOTF];
        if constexpr (NR == 1) {
            // w in [0,256) -> s in [128,384)
            __builtin_amdgcn_global_load_lds(
                (const __attribute__((address_space(1))) void*)(Rrow + c * HW + l4),
                (__attribute__((address_space(3))) void*)(base + 128 + l4),
                16, 0, 0);
        } else {
            // w in [128,512) -> s in [0,384): two overlapping 64-f4 instrs
            __builtin_amdgcn_global_load_lds(
                (const __attribute__((address_space(1))) void*)(Rrow + c * HW + 128 + l4),
                (__attribute__((address_space(3))) void*)(base + l4),
                16, 0, 0);
            __builtin_amdgcn_global_load_lds(
                (const __attribute__((address_space(1))) void*)(Rrow + c * HW + 256 + l4),
                (__attribute__((address_space(3))) void*)(base + 128 + l4),
                16, 0, 0);
        }
    };

    float4 Lpf[NSLOT];
    auto loadL = [&](int slot, int c) {
        Lpf[slot] = *reinterpret_cast<const float4*>(&Lrow[c * HW + w0]);
    };

    float acc[16][4];
    #pragma unroll
    for (int j = 0; j < 16; ++j)
        #pragma unroll
        for (int i = 0; i < 4; ++i)
            acc[j][i] = 0.f;

    // window: r[k] = R[w0 - d0 - 16 + k] (zeros where w<0 via pad).
    // slot coord of window start: s = (w0-d0-16) - wh + 128 = l4 + 112 - d0.
    // Range check: min (lane0,d0=48) = 64 >= 0; max (lane63,d0=0) read =
    // 364+19 = 383 < 384.  acc[j][i] uses r[16+i-j], k in [1,19].
    const int rbase = l4 + 112 - d0;

    auto compute = [&](int slot) {
        const float* Sb = &ring[slot * SLOTF];
        float r[20];
        #pragma unroll
        for (int q = 0; q < 5; ++q)
            *reinterpret_cast<float4*>(&r[q * 4]) =
                *reinterpret_cast<const float4*>(&Sb[rbase + q * 4]);
        const float4 Lv = Lpf[slot];
        #pragma unroll
        for (int j = 0; j < 16; ++j) {
            acc[j][0] = fmaf(Lv.x, r[16 - j], acc[j][0]);
            acc[j][1] = fmaf(Lv.y, r[17 - j], acc[j][1]);
            acc[j][2] = fmaf(Lv.z, r[18 - j], acc[j][2]);
            acc[j][3] = fmaf(Lv.w, r[19 - j], acc[j][3]);
        }
    };

    // prologue: chunks 0,1 in flight (2*(NR+1) vmem outstanding)
    stageR(0, 0); loadL(0, 0);
    stageR(1, 1); loadL(1, 1);

    // main loop, fully unrolled: every slot index / waitcnt is a literal.
    // Per iter: [lgkm0; stage(c+2)+loadL(c+2); vmcnt(2*(NR+1)-(NR+1))] ->
    // chunk c's NR+1 oldest ops complete, chunks c+1,c+2 stay in flight.
    #pragma unroll
    for (int c = 0; c < Cn - 2; ++c) {
        // prior ds_reads (slot being overwritten) must have executed
        asm volatile("s_waitcnt lgkmcnt(0)" ::: "memory");
        stageR((c + 2) % NSLOT, c + 2);
        loadL((c + 2) % NSLOT, c + 2);
        if constexpr (NR == 1) asm volatile("s_waitcnt vmcnt(4)" ::: "memory");
        else                   asm volatile("s_waitcnt vmcnt(6)" ::: "memory");
        compute(c % NSLOT);
    }
    // tail: chunks 30, 31 (no staging; drain counted)
    if constexpr (NR == 1) asm volatile("s_waitcnt vmcnt(2)" ::: "memory");
    else                   asm volatile("s_waitcnt vmcnt(3)" ::: "memory");
    compute((Cn - 2) % NSLOT);
    asm volatile("s_waitcnt vmcnt(0)" ::: "memory");
    compute((Cn - 1) % NSLOT);

    // epilogue: out[b][d0+j][h][w0..w0+3]
    constexpr float inv = 1.0f / 32.0f;
    float* op = out + ((b * Dn + d0) * Hn + h) * Wn + w0;
    #pragma unroll
    for (int j = 0; j < 16; ++j)
        *reinterpret_cast<float4*>(&op[j * HW]) =
            make_float4(acc[j][0] * inv, acc[j][1] * inv,
                        acc[j][2] * inv, acc[j][3] * inv);
}

__global__ __launch_bounds__(512, 4)
void cost_volume_kernel(const float* __restrict__ left,
                        const float* __restrict__ right,
                        float* __restrict__ out)
{
    __shared__ __align__(16) float Rs[8 * WAVE_LDS];   // 36,864 B

    const int tid  = threadIdx.x;
    const int wv   = tid >> 6;          // wave 0..7
    const int lane = tid & 63;
    const int dq   = wv & 3;            // d-quarter
    const int whi  = wv >> 2;           // w-half
    const int d0   = dq << 4;
    const int wh   = whi << 8;

    const int bh = blockIdx.x;
    const int b  = bh >> 8;             // H = 256
    const int h  = bh & (Hn - 1);

    const float* Lrow = left  + (b * Cn * Hn + h) * Wn;
    const float* Rrow = right + (b * Cn * Hn + h) * Wn;
    float* ring = &Rs[wv * WAVE_LDS];

    if (whi == 0)
        run_wave<1>(Lrow, Rrow, out, ring, lane, d0, wh, b, h);
    else
        run_wave<2>(Lrow, Rrow, out, ring, lane, d0, wh, b, h);
}

extern "C" void kernel_launch(void* const* d_in, const int* in_sizes, int n_in,
                              void* d_out, int out_size, void* d_ws, size_t ws_size,
                              hipStream_t stream) {
    const float* left  = (const float*)d_in[0];
    const float* right = (const float*)d_in[1];
    float* out = (float*)d_out;
    cost_volume_kernel<<<dim3(Bn * Hn), dim3(512), 0, stream>>>(left, right, out);
}

// Round 7
// 248.079 us; speedup vs baseline: 1.2428x; 1.2428x over previous
//
#include <hip/hip_runtime.h>

// Cost volume: out[b,d,h,w] = (w>=d) ? (1/32) * sum_c L[b,c,h,w]*R[b,c,h,w-d] : 0
// B=4, C=32, H=256, W=512, D=64, fp32 (no fp32-input MFMA on CDNA4).
//
// v7 (autonomy at occupancy, spill-proofed):
//   Evidence: v5 (wave-autonomous, no barriers) = 2.4x per-wave productivity
//   of every barrier-phased version, but only ~6 waves/CU resident. v6 tried
//   to scale it and spilled ~72 floats/thread to scratch (WRITE 131MB->285MB)
//   via register-array ring + 30x unrolled asm loop + dual template paths.
//   v7 keeps ZERO barriers and removes every spill trigger:
//   - 512-thr block = 8 autonomous waves, wave = (w-half, d-quarter).
//   - DT=16 x WT=4, acc[16][4]=64 floats (v1-proven budget, ~110 VGPR < 128
//     cap of __launch_bounds__(512,4)) -> 2 blocks/CU = 16 waves/CU.
//   - ONE uniform code path: every wave stages R[readbase, readbase+320)
//     (16B-width DMA x1 + 4B-width DMA x1) + L[wh, wh+256) (16B x1) into a
//     private 3-slot LDS ring (640 f/slot; slot = [64 zero pad][320 R][256 L]).
//     readbase = wh? 192:0. Pad gives w<0 zeros for wh=0 waves.
//   - Rolled main loop (#pragma unroll 1), scalar slot counters (SGPR
//     cselect), literal-indexed r[20]/acc only, counted vmcnt(6) per wave
//     (2 chunks of 3 DMAs always in flight), 2 peeled drain iterations.
//   LDS 8 x 7680 B = 61,440 B. Grid 1024 = 2 residency rounds.
//   Tripwire: WRITE_SIZE must be exactly 131072 KB (else spill returned).

constexpr int Bn = 4, Cn = 32, Hn = 256, Wn = 512, Dn = 64;
constexpr int HW = Hn * Wn;              // 131072
constexpr int SLOTR = 384;               // [64 pad][320 staged]
constexpr int SLOTF = SLOTR + 256;       // + L slice = 640 floats (2560 B)
constexpr int NSLOT = 3;
constexpr int WAVE_LDS = NSLOT * SLOTF;  // 1920 floats = 7680 B per wave

__global__ __launch_bounds__(512, 4)
void cost_volume_kernel(const float* __restrict__ left,
                        const float* __restrict__ right,
                        float* __restrict__ out)
{
    __shared__ __align__(16) float Rs[8 * WAVE_LDS];   // 61,440 B

    const int tid  = threadIdx.x;
    const int wv   = tid >> 6;           // wave 0..7
    const int lane = tid & 63;
    const int dq   = wv & 3;             // d-quarter
    const int whi  = wv >> 2;            // w-half index
    const int d0   = dq << 4;
    const int wh   = whi << 8;
    const int readbase = whi ? 192 : 0;  // R stage window [readbase, +320)

    const int bh = blockIdx.x;
    const int b  = bh >> 8;              // H = 256
    const int h  = bh & (Hn - 1);

    const float* Lrow = left  + (b * Cn * Hn + h) * Wn;   // channel stride HW
    const float* Rrow = right + (b * Cn * Hn + h) * Wn;
    float* ring = &Rs[wv * WAVE_LDS];

    // --- zero the pads of this wave's 3 slots: 3 x 64 floats = 48 float4.
    // Single-wave private region -> no barrier; lgkmcnt orders vs later reads.
    if (lane < NSLOT * 16) {
        const int slot = lane >> 4;
        const int o    = (lane & 15) << 2;
        *reinterpret_cast<float4*>(&ring[slot * SLOTF + o]) =
            make_float4(0.f, 0.f, 0.f, 0.f);
    }

    const int l4 = lane << 2;

    // stage chunk c -> slot: 3 DMA instrs, identical for every wave.
    // LDS dest = wave-uniform base + lane*width (legal for width 16 and 4).
    auto stage = [&](int slot, int c) {
        float* base = &ring[slot * SLOTF];
        const float* rsrc = Rrow + c * HW + readbase;
        __builtin_amdgcn_global_load_lds(
            (const __attribute__((address_space(1))) void*)(rsrc + l4),
            (__attribute__((address_space(3))) void*)(base + 64 + l4),
            16, 0, 0);
        __builtin_amdgcn_global_load_lds(
            (const __attribute__((address_space(1))) void*)(rsrc + 256 + lane),
            (__attribute__((address_space(3))) void*)(base + 320 + lane),
            4, 0, 0);
        __builtin_amdgcn_global_load_lds(
            (const __attribute__((address_space(1))) void*)(Lrow + c * HW + wh + l4),
            (__attribute__((address_space(3))) void*)(base + SLOTR + l4),
            16, 0, 0);
    };

    float acc[16][4];
    #pragma unroll
    for (int j = 0; j < 16; ++j)
        #pragma unroll
        for (int i = 0; i < 4; ++i)
            acc[j][i] = 0.f;

    // window: r[k] = R[w0 - d0 - 16 + k], k in [0,20). slot coord:
    // s = (w - (readbase - 64)) = w - readbase + 64.
    //   wh=0: rbase = l4 - d0 + 48   in [0,300],  max read 319 < 384. pads
    //         supply w<0 zeros; staged region starts at s=64 (w=0).
    //   wh=1: rbase = l4 - d0 + 112  in [64,364], max read 383 < 384.
    // All multiples of 4 -> aligned b128, 16B lane stride, conflict-free.
    const int rbase = l4 - d0 + 48 + (whi ? 64 : 0);

    auto compute = [&](int slot) {
        const float* Sb = &ring[slot * SLOTF];
        float r[20];
        #pragma unroll
        for (int q = 0; q < 5; ++q)
            *reinterpret_cast<float4*>(&r[q * 4]) =
                *reinterpret_cast<const float4*>(&Sb[rbase + q * 4]);
        const float4 Lv = *reinterpret_cast<const float4*>(&Sb[SLOTR + l4]);
        // acc[j][i] += L[w0+i] * R[w0+i-(d0+j)] -> r[16+i-j], k in [1,19]
        #pragma unroll
        for (int j = 0; j < 16; ++j) {
            acc[j][0] = fmaf(Lv.x, r[16 - j], acc[j][0]);
            acc[j][1] = fmaf(Lv.y, r[17 - j], acc[j][1]);
            acc[j][2] = fmaf(Lv.z, r[18 - j], acc[j][2]);
            acc[j][3] = fmaf(Lv.w, r[19 - j], acc[j][3]);
        }
    };

    // prologue: chunks 0,1 in flight (6 DMA outstanding for this wave)
    stage(0, 0);
    stage(1, 1);

    // main loop, rolled. Scalar slot counters (uniform -> SGPR cselect),
    // no runtime-indexed register arrays anywhere.
    // Per iter: stage chunk c+2 (9 outstanding) -> vmcnt(6) retires chunk
    // c's 3 oldest -> compute(c). WAR on slot (c+2)%3: its previous reads
    // were consumed by iter c-1's FMAs (program order), and the DMA write
    // lands hundreds of cycles after issue.
    int cur = 0;        // slot of chunk c
    int nx2 = 2;        // slot of chunk c+2
    #pragma unroll 1
    for (int c = 0; c < Cn - 2; ++c) {
        __builtin_amdgcn_sched_barrier(0);
        stage(nx2, c + 2);
        asm volatile("s_waitcnt vmcnt(6)" ::: "memory");
        __builtin_amdgcn_sched_barrier(0);
        compute(cur);
        cur = (cur == NSLOT - 1) ? 0 : cur + 1;
        nx2 = (nx2 == NSLOT - 1) ? 0 : nx2 + 1;
    }
    // peeled drain: chunks 30 (slot 0), 31 (slot 1)
    asm volatile("s_waitcnt vmcnt(3)" ::: "memory");
    __builtin_amdgcn_sched_barrier(0);
    compute(0);
    asm volatile("s_waitcnt vmcnt(0)" ::: "memory");
    __builtin_amdgcn_sched_barrier(0);
    compute(1);

    // --- epilogue: out[b][d0+j][h][wh + l4 .. +3], 1KB contiguous per j
    constexpr float inv = 1.0f / 32.0f;
    float* op = out + ((b * Dn + d0) * Hn + h) * Wn + wh + l4;
    #pragma unroll
    for (int j = 0; j < 16; ++j)
        *reinterpret_cast<float4*>(&op[j * HW]) =
            make_float4(acc[j][0] * inv, acc[j][1] * inv,
                        acc[j][2] * inv, acc[j][3] * inv);
}

extern "C" void kernel_launch(void* const* d_in, const int* in_sizes, int n_in,
                              void* d_out, int out_size, void* d_ws, size_t ws_size,
                              hipStream_t stream) {
    const float* left  = (const float*)d_in[0];
    const float* right = (const float*)d_in[1];
    float* out = (float*)d_out;
    cost_volume_kernel<<<dim3(Bn * Hn), dim3(512), 0, stream>>>(left, right, out);
}